// Round 7
// baseline (160.451 us; speedup 1.0000x reference)
//
#include <hip/hip_runtime.h>
#include <math.h>

#define NATOMS 1536
#define NSPEC 8
#define HID 64
#define NCEN 32
#define CUTOFF_R 5.0f
#define PI_F 3.14159265358979323846f
#define NBR_CAP 1024   // max in-cutoff neighbors per atom (~560 worst case here)

typedef __attribute__((ext_vector_type(8))) short short8;   // 8 bf16
typedef __attribute__((ext_vector_type(4))) float float4v;  // MFMA C/D

__device__ __forceinline__ float silu_f(float x) {
    return x / (1.f + __expf(-x));
}
__device__ __forceinline__ short f2bf(float x) {   // RNE f32->bf16
    unsigned u = __float_as_uint(x);
    u += 0x7fffu + ((u >> 16) & 1u);
    return (short)(u >> 16);
}
__device__ __forceinline__ float cut_f(float d) {
    return 0.5f * (__cosf((PI_F / CUTOFF_R) * d) + 1.f);
}

// ---------------------------------------------------------------------------
// K1 (R19) k_all: FULL per-atom fusion. One block per atom does:
//   scan (fused pair ballot -> pj_l holds LDS slot indices; pdlist DELETED)
//   register buckets -> charge MLP -> raw[i] (plain store)
//   per-block weight prep: w1f/w2f bf16 fragments direct from W1/W2 (same
//     index map as the old prep blocks), ctab row for si into LDS (same FMA
//     order as the old prep -> bitwise-identical ctab values)
//   pair MLP on its OWN pairs straight from LDS -> epp[i] (plain store)
// Rationale (R18 ledger): k_pairlr's pair block for atom a consumed exactly
// what k_one's block a had in LDS; the 7MB pdlist round-trip and a second
// serialized 1536-block launch existed only to re-materialize it. Weight
// tables are 44KB and L1/L2-hot; per-block rebuild is ~1us VALU.
// Zero global atomics (R16/R17 lesson). LDS ~34KB (s_part/s_tp unioned).
// ---------------------------------------------------------------------------
__global__ __launch_bounds__(256) void k_all(
    const int* __restrict__ species, const float* __restrict__ pos,
    const float* __restrict__ tq, const float* __restrict__ embed,
    const float* __restrict__ cW1, const float* __restrict__ cb1,
    const float* __restrict__ cW2, const float* __restrict__ cb2,
    const float* __restrict__ cW3, const float* __restrict__ cb3,
    const float* __restrict__ charge_scale,
    const float* __restrict__ W1, const float* __restrict__ b1,
    const float* __restrict__ W2, const float* __restrict__ b2,
    const float* __restrict__ W3, const float* __restrict__ b3,
    float* __restrict__ raw, double* __restrict__ epp)
{
    __shared__ float2 dc_l[NBR_CAP];            // 8 KB   (d, cut)
    __shared__ unsigned short spj_l[NBR_CAP];   // 2 KB   (species<<11 | j)
    __shared__ unsigned short pj_l[NBR_CAP];    // 2 KB   (LDS slot of pair)
    __shared__ float s_big[4 * 16 * 66];        // 16.9 KB (s_part | s_tp union)
    __shared__ float ctab_l[8 * 64];            // 2 KB   (ctab rows for si)
    __shared__ float s_x[292];
    __shared__ float s_h[64];
    __shared__ float s_red[256];
    __shared__ unsigned n_cnt, p_cnt;

    const int t = threadIdx.x;
    const int lane = t & 63;
    const int i = blockIdx.x;
    if (t == 0) { n_cnt = 0u; p_cnt = 0u; }
    __syncthreads();

    const float xi = pos[3*i+0], yi = pos[3*i+1], zi = pos[3*i+2];
    const int si = species[i];

    // ---- phase 1 (fused 1b): neighbor compaction + pair slot emission ----
    #pragma unroll
    for (int j0 = 0; j0 < NATOMS; j0 += 256) {
        const int j = j0 + t;
        const float dx = xi - pos[3*j+0];
        const float dy = yi - pos[3*j+1];
        const float dz = zi - pos[3*j+2];
        const float d = sqrtf(dx*dx + dy*dy + dz*dz + 1e-12f);
        const bool within = (d < CUTOFF_R) && (j != i);
        const unsigned long long m = __ballot((int)within);
        unsigned ofs = 0xffffffffu;
        if (within) {
            const int spj = species[j];
            const unsigned prefix = (unsigned)__popcll(m & ((1ull << lane) - 1ull));
            unsigned base = 0;
            if (prefix == 0) base = atomicAdd(&n_cnt, (unsigned)__popcll(m));
            base = (unsigned)__builtin_amdgcn_readfirstlane((int)base);
            ofs = base + prefix;
            if (ofs < NBR_CAP) {
                dc_l[ofs] = make_float2(d, cut_f(d));
                spj_l[ofs] = (unsigned short)((spj << 11) | j);
            }
        }
        const bool pair = within && (j > i) && (ofs < NBR_CAP);
        const unsigned long long mp = __ballot((int)pair);
        if (pair) {
            const unsigned pprefix = (unsigned)__popcll(mp & ((1ull << lane) - 1ull));
            unsigned pbase = 0;
            if (pprefix == 0) pbase = atomicAdd(&p_cnt, (unsigned)__popcll(mp));
            pbase = (unsigned)__builtin_amdgcn_readfirstlane((int)pbase);
            pj_l[pbase + pprefix] = (unsigned short)ofs;
        }
    }
    __syncthreads();
    const unsigned cnt = (n_cnt < NBR_CAP) ? n_cnt : NBR_CAP;
    const unsigned pn  = p_cnt;   // <= cnt <= NBR_CAP by construction

    // ---- phase 2: register-bucket basis accumulation (R8/R11-proven) ----
    {
        const int k = t & 31, gg = t >> 5;
        const float ck = (float)k * (CUTOFF_R / 31.f);
        float f0=0.f,f1=0.f,f2=0.f,f3=0.f,f4=0.f,f5=0.f,f6=0.f,f7=0.f;
        #pragma unroll 2
        for (unsigned n = (unsigned)gg; n < cnt; n += 8) {
            const float2 dc = dc_l[n];
            const float diff = dc.x - ck;
            const float v = __expf(-4.f * diff * diff) * dc.y;
            const int sp = (int)(spj_l[n] >> 11);
            f0 += (sp == 0) ? v : 0.f;
            f1 += (sp == 1) ? v : 0.f;
            f2 += (sp == 2) ? v : 0.f;
            f3 += (sp == 3) ? v : 0.f;
            f4 += (sp == 4) ? v : 0.f;
            f5 += (sp == 5) ? v : 0.f;
            f6 += (sp == 6) ? v : 0.f;
            f7 += (sp == 7) ? v : 0.f;
        }
        float* sp_g = &s_big[gg * 256 + k];
        sp_g[0*32] = f0; sp_g[1*32] = f1; sp_g[2*32] = f2; sp_g[3*32] = f3;
        sp_g[4*32] = f4; sp_g[5*32] = f5; sp_g[6*32] = f6; sp_g[7*32] = f7;
    }
    // ---- ctab rows for this si (same FMA order as old prep blocks) ----
    {
        const int o = t & 63;
        for (int sj2 = (t >> 6); sj2 < 8; sj2 += 4) {
            float acc = b1[o];
            #pragma unroll 4
            for (int k = 0; k < 32; k++) {
                const float a = embed[si * 32 + k];
                const float bb = embed[sj2 * 32 + k];
                acc += (a + bb) * W1[(32 + k) * HID + o];
                acc += (a * bb) * W1[(64 + k) * HID + o];
            }
            ctab_l[sj2 * 64 + o] = acc;
        }
    }
    __syncthreads();
    {
        float acc = 0.f;
        #pragma unroll
        for (int g2 = 0; g2 < 8; g2++) acc += s_big[g2 * 256 + t];
        s_x[t] = acc;
        if (t < 32) s_x[256 + t] = embed[si * 32 + t];
        if (t == 0) s_x[288] = tq[0];
    }
    __syncthreads();

    // ---- phase 3: charge MLP over s_x[289] (R13-exact orders) ----
    {
        const int g3 = t >> 6, o = t & 63;
        const int k0 = g3 * 72;
        const int k1 = (g3 == 3) ? 289 : (k0 + 72);
        float acc = 0.f;
        #pragma unroll 8
        for (int k = k0; k < k1; k++) acc += s_x[k] * cW1[k * 64 + o];
        s_big[g3 * 64 + o] = acc;
    }
    __syncthreads();
    if (t < 64) {
        const float a = cb1[t] + s_big[t] + s_big[64 + t]
                      + s_big[128 + t] + s_big[192 + t];
        s_h[t] = silu_f(a);
    }
    __syncthreads();
    {
        const int g3 = t >> 6, o = t & 63;
        float acc = 0.f;
        #pragma unroll
        for (int kk = 0; kk < 16; kk++) {
            const int k = g3 * 16 + kk;
            acc += s_h[k] * cW2[k * 64 + o];
        }
        s_big[g3 * 64 + o] = acc;
    }
    __syncthreads();
    if (t < 64) {
        const float a = cb2[t] + s_big[t] + s_big[64 + t]
                      + s_big[128 + t] + s_big[192 + t];
        float v = silu_f(a) * cW3[t];
        #pragma unroll
        for (int off = 32; off > 0; off >>= 1) v += __shfl_down(v, off);
        if (t == 0)
            raw[i] = (v + cb3[0]) * charge_scale[0];   // plain store
    }
    __syncthreads();   // s_big transitions from s_part to s_tp use

    // ---- phase 4: pair MLP on own pairs, straight from LDS ----
    const int wid = t >> 6;
    const int col = lane & 15;
    const int quad = lane >> 4;
    float esum = 0.f;

    if (pn > 0) {
        // per-lane bf16 fragments direct from W1/W2 (old prep's index map)
        short8 w1f[4], w2f[8];
        #pragma unroll
        for (int t4 = 0; t4 < 4; t4++)
            #pragma unroll
            for (int jj = 0; jj < 8; jj++)
                w1f[t4][jj] = f2bf(W1[((lane >> 4) * 8 + jj) * HID + t4 * 16 + (lane & 15)]);
        #pragma unroll
        for (int q8 = 0; q8 < 8; q8++)
            #pragma unroll
            for (int jj = 0; jj < 8; jj++)
                w2f[q8][jj] = f2bf(W2[((q8 >> 2) * 32 + (lane >> 4) * 8 + jj) * HID
                                      + (q8 & 3) * 16 + (lane & 15)]);
        float b2l[4], w3l[4];
        #pragma unroll
        for (int t4 = 0; t4 < 4; t4++) { b2l[t4] = b2[t4*16+col]; w3l[t4] = W3[t4*16+col]; }
        const float b3v = b3[0];
        float* tb = &s_big[wid * 1056];

        for (unsigned w = (unsigned)wid; w * 16u < pn; w += 4u) {
            unsigned p_idx = w * 16u + (unsigned)col;
            const bool valid = p_idx < pn;
            if (!valid) p_idx = pn - 1;
            const unsigned n = pj_l[p_idx];
            const float2 dc = dc_l[n];
            const float d = dc.x;
            const int spj = (int)(spj_l[n] >> 11);
            const float cut = valid ? dc.y : 0.f;
            if (lane < 16) esum += b3v * cut;

            short8 a1f;
            #pragma unroll
            for (int jj = 0; jj < 8; jj++) {
                const float ck = (float)(quad * 8 + jj) * (CUTOFF_R / 31.f);
                const float diff = d - ck;
                a1f[jj] = f2bf(__expf(-4.f * diff * diff));
            }

            int cmb[4]; float cutr[4];
            #pragma unroll
            for (int r = 0; r < 4; r++) {
                const int p = quad * 4 + r;
                cmb[r]  = __shfl(spj, p);
                cutr[r] = __shfl(cut, p);
            }

            float4v acc[4];
            #pragma unroll
            for (int t4 = 0; t4 < 4; t4++) {
                #pragma unroll
                for (int r = 0; r < 4; r++)
                    acc[t4][r] = ctab_l[cmb[r] * HID + t4 * 16 + col];
            }
            #pragma unroll
            for (int t4 = 0; t4 < 4; t4++)
                acc[t4] = __builtin_amdgcn_mfma_f32_16x16x32_bf16(a1f, w1f[t4], acc[t4], 0, 0, 0);

            #pragma unroll
            for (int t4 = 0; t4 < 4; t4++) {
                #pragma unroll
                for (int r = 0; r < 4; r++)
                    tb[(quad * 4 + r) * 66 + t4 * 16 + col] = silu_f(acc[t4][r]);
            }
            short8 a2f[2];
            #pragma unroll
            for (int c = 0; c < 2; c++) {
                #pragma unroll
                for (int jj = 0; jj < 8; jj++)
                    a2f[c][jj] = f2bf(tb[col * 66 + c * 32 + quad * 8 + jj]);
            }

            float4v acc2[4];
            #pragma unroll
            for (int t4 = 0; t4 < 4; t4++) {
                acc2[t4][0] = b2l[t4]; acc2[t4][1] = b2l[t4];
                acc2[t4][2] = b2l[t4]; acc2[t4][3] = b2l[t4];
            }
            #pragma unroll
            for (int c = 0; c < 2; c++) {
                #pragma unroll
                for (int t4 = 0; t4 < 4; t4++)
                    acc2[t4] = __builtin_amdgcn_mfma_f32_16x16x32_bf16(a2f[c], w2f[c*4+t4], acc2[t4], 0, 0, 0);
            }

            #pragma unroll
            for (int r = 0; r < 4; r++) {
                float part = 0.f;
                #pragma unroll
                for (int t4 = 0; t4 < 4; t4++) part += silu_f(acc2[t4][r]) * w3l[t4];
                esum += part * cutr[r];
            }
        }
    }

    s_red[t] = esum;
    __syncthreads();
    for (int s = 128; s > 0; s >>= 1) { if (t < s) s_red[t] += s_red[t + s]; __syncthreads(); }
    if (t == 0) epp[i] = (double)s_red[0];   // plain store
}

// ---------------------------------------------------------------------------
// K2 (R19) k_lr: 256 blocks — R18's LR branch, unchanged. Deterministic mean
// over raw[1536] per block (L1-resident), charges out, strided coulomb,
// plain elp stores. No atomics.
// ---------------------------------------------------------------------------
__global__ __launch_bounds__(256) void k_lr(
    const float* __restrict__ pos,
    const float* __restrict__ raw, const float* __restrict__ tq,
    const float* __restrict__ softening,
    double* __restrict__ elp, float* __restrict__ charges)
{
    __shared__ float s_red[256];
    const int t = threadIdx.x;
    const int b = blockIdx.x;      // 0..255

    float macc = 0.f;
    for (int idx = t; idx < NATOMS; idx += 256) macc += raw[idx];
    s_red[t] = macc;
    __syncthreads();
    for (int s = 128; s > 0; s >>= 1) { if (t < s) s_red[t] += s_red[t + s]; __syncthreads(); }
    const float mean = s_red[0] / (float)NATOMS;
    const float add = tq[0] / (float)NATOMS;
    __syncthreads();

    const int gid = b * 256 + t;
    if (gid < NATOMS) charges[gid] = raw[gid] - mean + add;

    const float sr = softening[0];
    const float sp = ((sr > 20.f) ? sr : log1pf(__expf(sr))) + 0.001f;
    const float sp2 = sp * sp;
    float acc = 0.f;
    for (int i = b; i < NATOMS; i += 256) {
        const float xi = pos[3*i+0], yi = pos[3*i+1], zi = pos[3*i+2];
        const float qi = raw[i] - mean + add;
        for (int j = i + 1 + t; j < NATOMS; j += 256) {
            const float dx = xi - pos[3*j+0];
            const float dy = yi - pos[3*j+1];
            const float dz = zi - pos[3*j+2];
            const float d2 = dx*dx + dy*dy + dz*dz + 1e-12f;
            const float qj = raw[j] - mean + add;
            acc += qi * qj * rsqrtf(d2 + sp2);
        }
    }
    s_red[t] = acc;
    __syncthreads();
    for (int s = 128; s > 0; s >>= 1) { if (t < s) s_red[t] += s_red[t + s]; __syncthreads(); }
    if (t == 0) elp[b] = (double)s_red[0];   // plain store
}

// ---------------------------------------------------------------------------
// K3 (R17-proven) k_final: one block sums epp[1536] + cs*elp[256] + bias.
// ---------------------------------------------------------------------------
__global__ __launch_bounds__(256) void k_final(
    const int* __restrict__ species, const float* __restrict__ atom_bias,
    const float* __restrict__ coulomb_scale,
    const double* __restrict__ epp, const double* __restrict__ elp,
    float* __restrict__ out_energy)
{
    __shared__ float s_red[256];
    __shared__ double s_redd[256];
    const int t = threadIdx.x;

    float bacc = 0.f;
    for (int idx = t; idx < NATOMS; idx += 256) bacc += atom_bias[species[idx]];
    s_red[t] = bacc;
    __syncthreads();
    for (int s = 128; s > 0; s >>= 1) { if (t < s) s_red[t] += s_red[t + s]; __syncthreads(); }

    const double cs = (double)coulomb_scale[0];
    double acc = 0.0;
    for (int idx = t; idx < NATOMS; idx += 256) acc += epp[idx];
    acc += cs * elp[t];
    s_redd[t] = acc;
    __syncthreads();
    for (int s = 128; s > 0; s >>= 1) { if (t < s) s_redd[t] += s_redd[t + s]; __syncthreads(); }
    if (t == 0) out_energy[0] = (float)(s_redd[0] + (double)s_red[0]);
}

// ---------------------------------------------------------------------------
// Workspace layout (R19) — NO memset, NO global atomics, pdlist DELETED.
// Every slot read is written unconditionally each iteration:
//   raw/epp by the 1536 k_all blocks, elp by the 256 k_lr blocks.
//   [64,6208)      raw[1536] f32
//   [8192,20480)   epp[1536] f64
//   [20480,22528)  elp[256] f64
// ---------------------------------------------------------------------------
extern "C" void kernel_launch(void* const* d_in, const int* in_sizes, int n_in,
                              void* d_out, int out_size, void* d_ws, size_t ws_size,
                              hipStream_t stream) {
    const int*   species       = (const int*)d_in[0];
    const float* pos           = (const float*)d_in[1];
    const float* tq            = (const float*)d_in[2];
    const float* embed         = (const float*)d_in[3];
    const float* W1            = (const float*)d_in[4];
    const float* b1            = (const float*)d_in[5];
    const float* W2            = (const float*)d_in[6];
    const float* b2            = (const float*)d_in[7];
    const float* W3            = (const float*)d_in[8];
    const float* b3            = (const float*)d_in[9];
    const float* atom_bias     = (const float*)d_in[10];
    const float* cW1           = (const float*)d_in[11];
    const float* cb1           = (const float*)d_in[12];
    const float* cW2           = (const float*)d_in[13];
    const float* cb2           = (const float*)d_in[14];
    const float* cW3           = (const float*)d_in[15];
    const float* cb3           = (const float*)d_in[16];
    const float* charge_scale  = (const float*)d_in[17];
    const float* coulomb_scale = (const float*)d_in[18];
    const float* softening     = (const float*)d_in[19];

    char* ws = (char*)d_ws;
    float*  raw = (float*)(ws + 64);       // 6144 B
    double* epp = (double*)(ws + 8192);    // 12288 B
    double* elp = (double*)(ws + 20480);   // 2048 B

    float* out     = (float*)d_out;
    float* charges = out + 1;   // output layout: [energy, charges[1536]]

    k_all<<<NATOMS, 256, 0, stream>>>(
        species, pos, tq, embed,
        cW1, cb1, cW2, cb2, cW3, cb3, charge_scale,
        W1, b1, W2, b2, W3, b3,
        raw, epp);
    k_lr<<<256, 256, 0, stream>>>(
        pos, raw, tq, softening, elp, charges);
    k_final<<<1, 256, 0, stream>>>(
        species, atom_bias, coulomb_scale, epp, elp, out);
}